// Round 10
// baseline (749.991 us; speedup 1.0000x reference)
//
#include <hip/hip_runtime.h>
#include <stdint.h>

typedef __bf16 bf16;
typedef __bf16   bf16x8 __attribute__((ext_vector_type(8)));
typedef short    s16x8  __attribute__((ext_vector_type(8)));
typedef float    fx4    __attribute__((ext_vector_type(4)));

#define NB 32
#define NT 1500
#define NF 512
#define NM (NB*NT)      // 48000
#define KW 31
#define EPSF 1e-5f

__device__ __forceinline__ float dscale(const float* a) {
  return fmaxf(a[0] * (1.0f/127.0f), 1e-8f);
}
__device__ __forceinline__ float fq_int(float x, float inv_s) {
  return fminf(fmaxf(rintf(x*inv_s), -128.0f), 127.0f);
}
__device__ __forceinline__ void block_amax(float v, float* dst) {
  __shared__ float red[8];
  #pragma unroll
  for (int o = 32; o > 0; o >>= 1) v = fmaxf(v, __shfl_xor(v, o));
  if ((threadIdx.x & 63) == 0) red[threadIdx.x >> 6] = v;
  __syncthreads();
  if (threadIdx.x == 0) {
    int nw = blockDim.x >> 6;
    float m = red[0];
    for (int i = 1; i < nw; i++) m = fmaxf(m, red[i]);
    atomicMax((unsigned int*)dst, __float_as_uint(m));
  }
}

__device__ __forceinline__ float amax_loop(const float* p, long n4, int bid, int gsz) {
  float am = 0.f;
  long i = (long)bid * 256 + threadIdx.x;
  long stride = (long)gsz * 256;
  for (; i < n4; i += stride) {
    fx4 v = ((const fx4*)p)[i];
    #pragma unroll
    for (int j = 0; j < 4; j++) am = fmaxf(am, fabsf(v[j]));
  }
  return am;
}

// ---------- pack helper: fp32 [R x 512] -> int-grid bf16, MFMA-fragment-packed ----
// Panel (r16,kb): 16 rows x 32 cols as 64 chunks of 8 bf16; chunk quad*16+m16 =
// row m16, cols kb*32+quad*8..+7. Wave fragment load = 1KB contiguous.
__device__ __forceinline__ void pack_range(const float* __restrict__ src,
                                           bf16* __restrict__ dst, int R,
                                           float inv_s, int bid, int nb) {
  int total = R * 64;
  for (int t = bid*256 + threadIdx.x; t < total; t += nb*256) {
    int r = t >> 6, q8 = t & 63;
    const float* s = src + (size_t)r*512 + q8*8;
    fx4 v0 = *(const fx4*)s, v1 = *(const fx4*)(s+4);
    bf16x8 o;
    #pragma unroll
    for (int j = 0; j < 4; j++) { o[j] = (bf16)fq_int(v0[j], inv_s); o[4+j] = (bf16)fq_int(v1[j], inv_s); }
    int r16 = r >> 4, m16 = r & 15, kb = q8 >> 2, quad = q8 & 3;
    size_t chunk = ((size_t)r16*16 + kb)*64 + quad*16 + m16;
    ((bf16x8*)dst)[chunk] = o;
  }
}

// ---------- LayerNorm (blocks 0..1535) + weight absmax (blocks 1536..1927) ----
__global__ void ln_amaxw_k(const float* __restrict__ x, const float* __restrict__ g,
                           const float* __restrict__ be, float* __restrict__ t,
                           const float* __restrict__ W1, const float* __restrict__ W2,
                           const float* __restrict__ dwp, float* amax) {
  int bx = blockIdx.x;
  if (bx >= 1536) {
    float am; float* dst;
    if (bx < 1792)      { am = amax_loop(W1,  131072, bx-1536, 256); dst = amax + 1; }
    else if (bx < 1920) { am = amax_loop(W2,  65536,  bx-1792, 128); dst = amax + 2; }
    else                { am = amax_loop(dwp, 3968,   bx-1920, 8);   dst = amax + 3; }
    block_amax(am, dst);
    return;
  }
  int lane = threadIdx.x & 63;
  const int wavesTotal = 1536 * 4;   // 1536 blocks x 4 waves
  int wave = ((bx * 256) + threadIdx.x) >> 6;
  fx4 g0 = ((const fx4*)g)[lane],  g1 = ((const fx4*)g)[lane+64];
  fx4 b0 = ((const fx4*)be)[lane], b1v = ((const fx4*)be)[lane+64];
  float gf[8], bff[8];
  #pragma unroll
  for (int j = 0; j < 4; j++) { gf[j] = g0[j]; gf[4+j] = g1[j]; bff[j] = b0[j]; bff[4+j] = b1v[j]; }
  float am = 0.f;
  for (int row = wave; row < NM; row += wavesTotal) {
    const fx4* xr = (const fx4*)(x + (long)row*NF);
    fx4 x0 = xr[lane], x1 = xr[lane+64];
    float xf[8]; float s = 0.f;
    #pragma unroll
    for (int j = 0; j < 4; j++) { xf[j] = x0[j]; xf[4+j] = x1[j]; }
    #pragma unroll
    for (int j = 0; j < 8; j++) s += xf[j];
    #pragma unroll
    for (int o = 32; o > 0; o >>= 1) s += __shfl_xor(s, o);
    float mu = s * (1.0f/NF);
    float vs = 0.f;
    #pragma unroll
    for (int j = 0; j < 8; j++) { float d = xf[j]-mu; vs += d*d; }
    #pragma unroll
    for (int o = 32; o > 0; o >>= 1) vs += __shfl_xor(vs, o);
    float inv = rsqrtf(vs*(1.0f/NF) + EPSF);
    fx4 o0, o1;
    #pragma unroll
    for (int j = 0; j < 4; j++) {
      float v = (xf[j]-mu)*inv*gf[j] + bff[j];
      am = fmaxf(am, fabsf(v)); o0[j] = v;
    }
    #pragma unroll
    for (int j = 0; j < 4; j++) {
      float v = (xf[4+j]-mu)*inv*gf[4+j] + bff[4+j];
      am = fmaxf(am, fabsf(v)); o1[j] = v;
    }
    ((fx4*)(t + (long)row*NF))[lane]    = o0;
    ((fx4*)(t + (long)row*NF))[lane+64] = o1;
  }
  block_amax(am, amax);
}

// ---------- fused pack: t (blocks 0..4095), W1 (4096..4351), W2 (4352..4479) ----
__global__ void pack_all_k(const float* __restrict__ t_raw, bf16* __restrict__ t_q,
                           const float* __restrict__ W1, bf16* __restrict__ W1q,
                           const float* __restrict__ W2, bf16* __restrict__ W2q,
                           const float* amax) {
  int bx = blockIdx.x;
  if (bx < 4096)      pack_range(t_raw, t_q, NM,   1.0f/dscale(amax+0), bx,      4096);
  else if (bx < 4352) pack_range(W1,    W1q, 1024, 1.0f/dscale(amax+1), bx-4096, 256);
  else                pack_range(W2,    W2q, 512,  1.0f/dscale(amax+2), bx-4352, 128);
}

// ---------- standalone pack (p before gemm2) ----------
__global__ void quant_pack(const float* __restrict__ src, bf16* __restrict__ dst,
                           int R, const float* amax) {
  pack_range(src, dst, R, 1.0f/dscale(amax), blockIdx.x, gridDim.x);
}

// ---------- final fake-quant fp32 in place ----------
__global__ void quant_deq_f32(float* __restrict__ p, long n4, const float* amax) {
  float s = dscale(amax);
  float inv_s = 1.0f / s;
  long i = (long)blockIdx.x * blockDim.x + threadIdx.x;
  long stride = (long)gridDim.x * blockDim.x;
  for (; i < n4; i += stride) {
    fx4 v = ((fx4*)p)[i];
    fx4 o;
    #pragma unroll
    for (int j = 0; j < 4; j++) o[j] = fq_int(v[j], inv_s) * s;
    ((fx4*)p)[i] = o;
  }
}

// ---------- MFMA GEMM over fragment-packed operands ----------
// C[M,N] = (qA @ qBt^T)*sa*sb + bias. 256 thr / 4 waves / 64x64 per wave.
// launch_bounds(256,4): cap regs at 128/wave so 4 waves/SIMD cover load latency.
template<int NBN>   // N = NBN*128
__global__ __launch_bounds__(256, 4) void gemm_k(
    const bf16* __restrict__ A, const bf16* __restrict__ Bt,
    const float* __restrict__ bias, float* __restrict__ C,
    const float* amaxA, const float* amaxB, float* amaxC) {
  const int N = NBN * 128;
  int id = blockIdx.x;
  int bn = (id >> 3) % NBN;
  int bm = 8 * (id / (8 * NBN)) + (id & 7);
  if (bm >= 375) return;
  int lane = threadIdx.x & 63;
  int w = threadIdx.x >> 6;
  int wm = w >> 1, wn = w & 1;
  int quad = lane >> 4;
  int m16 = lane & 15;

  fx4 acc[4][4];
  #pragma unroll
  for (int i = 0; i < 4; i++)
    #pragma unroll
    for (int j = 0; j < 4; j++) acc[i][j] = fx4{0.f,0.f,0.f,0.f};

  const bf16* baseA = A  + ((size_t)(bm*8 + wm*4)*16)*512 + lane*8;
  const bf16* baseB = Bt + ((size_t)(bn*8 + wn*4)*16)*512 + lane*8;

  #pragma unroll
  for (int kb = 0; kb < 16; kb++) {
    s16x8 aF[4], bF[4];
    #pragma unroll
    for (int i = 0; i < 4; i++) aF[i] = *(const s16x8*)(baseA + i*8192 + kb*512);
    #pragma unroll
    for (int j = 0; j < 4; j++) bF[j] = *(const s16x8*)(baseB + j*8192 + kb*512);
    #pragma unroll
    for (int i = 0; i < 4; i++)
      #pragma unroll
      for (int j = 0; j < 4; j++)
        acc[i][j] = __builtin_amdgcn_mfma_f32_16x16x32_bf16(aF[i], bF[j], acc[i][j], 0, 0, 0);
  }

  float ab = dscale(amaxA) * dscale(amaxB);
  float am = 0.f;
  #pragma unroll
  for (int j = 0; j < 4; j++) {
    int col = bn*128 + wn*64 + j*16 + m16;
    float bv = bias[col];
    #pragma unroll
    for (int i = 0; i < 4; i++) {
      int row0 = bm*128 + wm*64 + i*16 + quad*4;
      #pragma unroll
      for (int rr = 0; rr < 4; rr++) {
        float v = acc[i][j][rr]*ab + bv;
        am = fmaxf(am, fabsf(v));
        C[(long)(row0+rr)*N + col] = v;
      }
    }
  }
  block_amax(am, amaxC);
}

// ---------- GLU + transpose [BT,1024] -> v[B,F,T] ----------
__global__ void glu_k(const float* __restrict__ u, float* __restrict__ v,
                      const float* amaxU, float* amaxV) {
  __shared__ float lds[32][33];
  float s = dscale(amaxU);
  float inv_s = 1.0f / s;
  float am = 0.f;
  int tx = threadIdx.x & 31, ty = threadIdx.x >> 5;   // 32 x 8
  const int ntile = (NM/32) * (NF/32);
  for (int tile = blockIdx.x; tile < ntile; tile += gridDim.x) {
    int btT = tile % (NM/32), fT = tile / (NM/32);
    int bt0 = btT*32, f0 = fT*32;
    __syncthreads();
    #pragma unroll
    for (int sI = 0; sI < 4; sI++) {
      int rr = ty + sI*8;
      long base = (long)(bt0 + rr)*(2*NF) + f0 + tx;
      float a = fq_int(u[base], inv_s) * s;
      float g = fq_int(u[base + NF], inv_s) * s;
      float val = a * (1.0f/(1.0f + expf(-g)));
      lds[tx][rr] = val;
      am = fmaxf(am, fabsf(val));
    }
    __syncthreads();
    #pragma unroll
    for (int sI = 0; sI < 4; sI++) {
      int f = f0 + ty + sI*8;
      int bt = bt0 + tx;
      int b = bt / NT, t = bt - b*NT;
      v[((long)b*NF + f)*NT + t] = lds[ty + sI*8][tx];
    }
  }
  block_amax(am, amaxV);
}

// ---------- depthwise conv K=31 on [B,F,T] ----------
__global__ void dwconv_k(const float* __restrict__ v, const float* __restrict__ w,
                         const float* __restrict__ wb, float* __restrict__ y,
                         const float* amaxV, const float* amaxW, float* amaxY) {
  __shared__ float z[NT + KW - 1];
  __shared__ float wl[KW];
  float sv = dscale(amaxV); float inv_sv = 1.0f/sv;
  float sw = dscale(amaxW); float inv_sw = 1.0f/sw;
  float am = 0.f;
  for (int row = blockIdx.x; row < NB*NF; row += gridDim.x) {
    int f = row & (NF-1);
    __syncthreads();
    if (threadIdx.x < KW)
      wl[threadIdx.x] = fq_int(w[f*KW + threadIdx.x], inv_sw) * sw;
    long base = (long)row * NT;
    for (int i = threadIdx.x; i < NT + KW - 1; i += 256) {
      int t = i - (KW-1)/2;
      float val = 0.f;
      if (t >= 0 && t < NT) val = fq_int(v[base + t], inv_sv) * sv;
      z[i] = val;
    }
    __syncthreads();
    float bias = wb[f];
    for (int t = threadIdx.x; t < NT; t += 256) {
      float acc = 0.f;
      #pragma unroll
      for (int k = 0; k < KW; k++) acc += z[t + k] * wl[k];
      acc += bias;
      am = fmaxf(am, fabsf(acc));
      y[base + t] = acc;
    }
  }
  block_amax(am, amaxY);
}

// ---------- BN stats: exact int sums, 4-way batch split + atomic partials ----------
// grid 2048: f = id&511, batch group = id>>9 (8 b's each). Zero-init via memset.
__global__ void bnstats_k(const float* __restrict__ y, const float* amaxY,
                          int* bn_s1, int* bn_s2) {
  float inv_sy = 1.0f/dscale(amaxY);
  int f = blockIdx.x & 511;
  int bg = blockIdx.x >> 9;
  int s1 = 0, s2 = 0;
  for (int b = bg*8; b < bg*8+8; b++) {
    const fx4* base = (const fx4*)(y + ((long)b*NF + f)*NT);
    for (int i = threadIdx.x; i < NT/4; i += blockDim.x) {
      fx4 v = base[i];
      #pragma unroll
      for (int j = 0; j < 4; j++) {
        int q = (int)fq_int(v[j], inv_sy);
        s1 += q; s2 += q*q;
      }
    }
  }
  #pragma unroll
  for (int o = 32; o > 0; o >>= 1) { s1 += __shfl_xor(s1, o); s2 += __shfl_xor(s2, o); }
  __shared__ int rs1[4], rs2[4];
  if ((threadIdx.x & 63) == 0) { rs1[threadIdx.x>>6] = s1; rs2[threadIdx.x>>6] = s2; }
  __syncthreads();
  if (threadIdx.x == 0) {
    atomicAdd(bn_s1 + f, rs1[0]+rs1[1]+rs1[2]+rs1[3]);
    atomicAdd(bn_s2 + f, rs2[0]+rs2[1]+rs2[2]+rs2[3]);
  }
}

// ---------- BN apply + silu + transpose [B,F,T] -> p[BT,F] ----------
__global__ void bnsilu_k(const float* __restrict__ y, const float* __restrict__ bg,
                         const float* __restrict__ bb, const float* amaxY,
                         const int* bn_s1, const int* bn_s2,
                         float* __restrict__ p, float* amaxP) {
  __shared__ float lds[32][33];
  float sy = dscale(amaxY); float inv_sy = 1.0f/sy;
  float am = 0.f;
  int tx = threadIdx.x & 31, ty = threadIdx.x >> 5;
  const int TTILES = (NT + 31)/32;
  const int ntile = NB * (NF/32) * TTILES;
  for (int tile = blockIdx.x; tile < ntile; tile += gridDim.x) {
    int b = tile / ((NF/32)*TTILES);
    int rem = tile % ((NF/32)*TTILES);
    int fT = rem / TTILES, tT = rem % TTILES;
    int f0 = fT*32, t0 = tT*32;
    __syncthreads();
    #pragma unroll
    for (int sI = 0; sI < 4; sI++) {
      int f = f0 + ty + sI*8;
      int t = t0 + tx;
      if (t < NT) {
        double sd = (double)sy;
        double mean_d = (double)bn_s1[f] * sd / (double)NM;
        double var_d  = (double)bn_s2[f] * sd * sd / (double)NM - mean_d*mean_d;
        float meanf = (float)mean_d;
        float rinv  = rsqrtf((float)var_d + EPSF);
        float zq = fq_int(y[((long)b*NF + f)*NT + t], inv_sy) * sy;
        float val = (zq - meanf)*rinv*bg[f] + bb[f];
        val = val / (1.0f + expf(-val));
        am = fmaxf(am, fabsf(val));
        lds[tx][ty + sI*8] = val;
      }
    }
    __syncthreads();
    #pragma unroll
    for (int sI = 0; sI < 4; sI++) {
      int t = t0 + ty + sI*8;
      if (t < NT)
        p[((long)b*NT + t)*NF + f0 + tx] = lds[ty + sI*8][tx];
    }
  }
  block_amax(am, amaxP);
}

extern "C" void kernel_launch(void* const* d_in, const int* in_sizes, int n_in,
                              void* d_out, int out_size, void* d_ws, size_t ws_size,
                              hipStream_t stream) {
  const float* x  = (const float*)d_in[0];
  const float* lg = (const float*)d_in[1];
  const float* lb = (const float*)d_in[2];
  const float* W1 = (const float*)d_in[3];
  const float* b1 = (const float*)d_in[4];
  const float* dw = (const float*)d_in[5];
  const float* db = (const float*)d_in[6];
  const float* bg = (const float*)d_in[7];
  const float* bb = (const float*)d_in[8];
  const float* W2 = (const float*)d_in[9];
  const float* b2 = (const float*)d_in[10];
  float* out = (float*)d_out;

  char* ws = (char*)d_ws;
  float* amax  = (float*)ws;               // [0]=t [1]=W1 [2]=W2 [3]=dw [4]=u [5]=v [6]=y [7]=p [8]=r
  int*   bn_s1 = (int*)(ws + 1024);        // 512 ints (zeroed by memset)
  int*   bn_s2 = (int*)(ws + 4096);        // 512 ints (zeroed by memset)
  char* H = ws + 8192;
  float* t_raw = (float*)H;                       // dies after pack
  float* u_raw = (float*)H;                       // [0, 196.6M)
  bf16*  t_q   = (bf16*)(H + 196608000);
  float* y     = (float*)H;                       // over dead u
  float* p_raw = (float*)(H + 98304000);
  bf16*  p_q   = (bf16*)(H + 196608000);          // over dead t_q
  bf16*  W1q   = (bf16*)(H + 245760000);
  bf16*  W2q   = (bf16*)(H + 246808576);
  float* v = (float*)d_out;
  float* r = (float*)d_out;

  hipMemsetAsync(ws, 0, 8192, stream);

  ln_amaxw_k<<<1928, 256, 0, stream>>>(x, lg, lb, t_raw, W1, W2, dw, amax);
  pack_all_k<<<4480, 256, 0, stream>>>(t_raw, t_q, W1, W1q, W2, W2q, amax);
  gemm_k<8><<<3008, 256, 0, stream>>>(t_q, W1q, b1, u_raw, amax+0, amax+1, amax+4);
  glu_k<<<4096, 256, 0, stream>>>(u_raw, v, amax+4, amax+5);
  dwconv_k<<<2048, 256, 0, stream>>>(v, dw, db, y, amax+5, amax+3, amax+6);
  bnstats_k<<<2048, 256, 0, stream>>>(y, amax+6, bn_s1, bn_s2);
  bnsilu_k<<<4096, 256, 0, stream>>>(y, bg, bb, amax+6, bn_s1, bn_s2, p_raw, amax+7);
  quant_pack<<<4096, 256, 0, stream>>>(p_raw, p_q, NM, amax+7);
  gemm_k<4><<<1504, 256, 0, stream>>>(p_q, W2q, b2, r, amax+7, amax+2, amax+8);
  quant_deq_f32<<<2048, 256, 0, stream>>>(out, 24576000/4, amax+8);
}